// Round 9
// baseline (56.513 us; speedup 1.0000x reference)
//
#include <hip/hip_runtime.h>
#include <cstdint>
#include <cstddef>

// ContrastiveLoss: B=8192, D=256 fp32 inputs.
// loss = mean_b [ log( exp(2*pos_b) + sum_c exp(2*z_i[b].z_k[c]) ) - 2*pos_b ]
// R8: LDS-free, barrier-free MFMA GEMM over fragment-PACKED operands.
//   prep: normalize, scale z_i by 2, and write both matrices in MFMA
//         fragment order: frag(g,kt) = 1 KB contiguous block, lane l owns
//         bytes [l*16, +16)  (row = g*16 + (l&15), k = kt*32 + (l>>4)*8).
//   sim:  every A/B fragment load is ONE coalesced global_load_dwordx4
//         (L2-resident); waves free-run with double-buffered fragment regs;
//         no __syncthreads/s_barrier anywhere in the loop.
// exp fused per tile; shuffle-reduce + atomics once per block.

constexpr int   D_DIM = 256;
constexpr float INV_T = 2.0f;   // 1/T, T=0.5

constexpr int BM = 128;         // block rows
constexpr int BN = 128;         // cols per tile
constexpr int NT = 4;           // column tiles per block (block = 128 x 512)

typedef __attribute__((ext_vector_type(8))) short  bf16x8;
typedef __attribute__((ext_vector_type(4))) float  f32x4;

__device__ __forceinline__ unsigned short f32_to_bf16(float f) {
    unsigned int u = __float_as_uint(f);
    u += 0x7FFFu + ((u >> 16) & 1u);          // RNE
    return (unsigned short)(u >> 16);
}

// ---------------------------------------------------------------------------
// Kernel 1: per-16-row block: norms, pos_logit, rowsum init, and PACKED
// bf16 output. Thread t: row_local = t>>4, chunk c = t&15 (16 elems).
// Row's 16 threads are contiguous lanes -> shfl_xor(1,2,4,8) reduces.
// ---------------------------------------------------------------------------
__global__ __launch_bounds__(256) void prep_kernel(
    const float* __restrict__ ei, const float* __restrict__ ej,
    const float* __restrict__ ek,
    unsigned short* __restrict__ zip, unsigned short* __restrict__ zkp,
    float* __restrict__ pos_logit, float* __restrict__ rowsum)
{
    const int t  = (int)threadIdx.x;
    const int rl = t >> 4;              // row within group (0..15)
    const int c  = t & 15;              // 16-elem chunk (0..15)
    const int g  = (int)blockIdx.x;     // row group
    const int row = g * 16 + rl;

    const float4* pi = (const float4*)(ei + (size_t)row * D_DIM + c * 16);
    const float4* pj = (const float4*)(ej + (size_t)row * D_DIM + c * 16);
    const float4* pk = (const float4*)(ek + (size_t)row * D_DIM + c * 16);
    float4 vi[4], vj[4], vk[4];
    #pragma unroll
    for (int q = 0; q < 4; ++q) { vi[q] = pi[q]; vj[q] = pj[q]; vk[q] = pk[q]; }

    float ssi = 0.f, ssj = 0.f, ssk = 0.f, dij = 0.f;
    #pragma unroll
    for (int q = 0; q < 4; ++q) {
        ssi += vi[q].x*vi[q].x + vi[q].y*vi[q].y + vi[q].z*vi[q].z + vi[q].w*vi[q].w;
        ssj += vj[q].x*vj[q].x + vj[q].y*vj[q].y + vj[q].z*vj[q].z + vj[q].w*vj[q].w;
        ssk += vk[q].x*vk[q].x + vk[q].y*vk[q].y + vk[q].z*vk[q].z + vk[q].w*vk[q].w;
        dij += vi[q].x*vj[q].x + vi[q].y*vj[q].y + vi[q].z*vj[q].z + vi[q].w*vj[q].w;
    }
    #pragma unroll
    for (int off = 1; off <= 8; off <<= 1) {    // reduce over the 16 c-lanes
        ssi += __shfl_xor(ssi, off);
        ssj += __shfl_xor(ssj, off);
        ssk += __shfl_xor(ssk, off);
        dij += __shfl_xor(dij, off);
    }
    const float ri = INV_T / fmaxf(sqrtf(ssi), 1e-12f);   // fold 1/T into z_i
    const float rj = 1.0f  / fmaxf(sqrtf(ssj), 1e-12f);
    const float rk = 1.0f  / fmaxf(sqrtf(ssk), 1e-12f);

    // pack: this thread's 16 elems are k in [c*16, c*16+16):
    //   kt = c>>1; first 8 -> ksub = 2*(c&1), second 8 -> ksub+1.
    bf16x8 hi0, hi1, hk0, hk1;
    #pragma unroll
    for (int q = 0; q < 4; ++q) {
        const float* fi = &vi[q].x;
        const float* fk = &vk[q].x;
        #pragma unroll
        for (int e = 0; e < 4; ++e) {
            const int idx = q * 4 + e;          // 0..15
            const unsigned short bi = f32_to_bf16(fi[e] * ri);
            const unsigned short bk = f32_to_bf16(fk[e] * rk);
            if (idx < 8) { hi0[idx] = (short)bi; hk0[idx] = (short)bk; }
            else         { hi1[idx - 8] = (short)bi; hk1[idx - 8] = (short)bk; }
        }
    }
    const int kt    = c >> 1;
    const int lane0 = rl + 16 * ((c & 1) * 2);
    const size_t fb = ((size_t)g * 8 + kt) * 512;    // frag base (elems)
    *(bf16x8*)(zip + fb + (size_t)lane0 * 8)        = hi0;
    *(bf16x8*)(zip + fb + (size_t)(lane0 + 16) * 8) = hi1;
    *(bf16x8*)(zkp + fb + (size_t)lane0 * 8)        = hk0;
    *(bf16x8*)(zkp + fb + (size_t)(lane0 + 16) * 8) = hk1;

    if (c == 0) {
        pos_logit[row] = dij * ri * rj;   // ri already includes 1/T
        rowsum[row]    = 0.0f;
    }
}

// ---------------------------------------------------------------------------
// Kernel 2: rows [by*128,+128) x cols [bx*512,+512) of exp-sum of
// (2*Z_i) . Z_k^T. No LDS, no barriers. 4 waves (2x2), wave tile 64x64 =
// 4x4 frags of 16x16x32 bf16. A/B fragments double-buffered in registers,
// refilled right after consumption (~1.5-step prefetch distance).
// Frag address: base + ((group*8 + kt) << 9) + l*8   (elems).
// ---------------------------------------------------------------------------
__global__ __launch_bounds__(256, 2) void sim_mfma_kernel(
    const unsigned short* __restrict__ zip, const unsigned short* __restrict__ zkp,
    float* __restrict__ rowsum)
{
    const int t  = (int)threadIdx.x;
    const int w  = t >> 6;        // wave 0..3
    const int l  = t & 63;
    const int wr = w >> 1;        // wave row (0..1)
    const int wc = w & 1;         // wave col (0..1)
    const int rowBase = (int)blockIdx.y * BM;

    // A frag (mi, kt): Abase + ((mi*8 + kt) << 9)
    const unsigned short* Abase =
        zip + (((size_t)blockIdx.y * 8 + wr * 4) * 8) * 512 + (size_t)l * 8;
    // B frag (nt, ni, kt): Bbase + (((nt*8 + ni)*8 + kt) << 9)
    const unsigned short* Bbase =
        zkp + (((size_t)blockIdx.x * 32 + wc * 4) * 8) * 512 + (size_t)l * 8;

    #define LDA(dst, s) {                                                     \
        const int kt_ = (s) & 7;                                              \
        _Pragma("unroll")                                                     \
        for (int mi = 0; mi < 4; ++mi)                                        \
            dst[mi] = *(const bf16x8*)(Abase + ((mi * 8 + kt_) << 9));        \
    }
    #define LDB(dst, s) {                                                     \
        const int nt_ = (s) >> 3, kt_ = (s) & 7;                              \
        _Pragma("unroll")                                                     \
        for (int ni = 0; ni < 4; ++ni)                                        \
            dst[ni] = *(const bf16x8*)(Bbase + (((nt_ * 8 + ni) * 8 + kt_) << 9)); \
    }

    bf16x8 aX[4], aY[4], bX[4], bY[4];
    LDA(aX, 0); LDB(bX, 0);           // step 0 -> X
    LDA(aY, 1); LDB(bY, 1);           // step 1 -> Y

    float partAcc[4][4] = {};

    for (int nt = 0; nt < NT; ++nt) {
        f32x4 acc[4][4] = {};

        #pragma unroll
        for (int kt = 0; kt < 8; ++kt) {
            const int s  = nt * 8 + kt;            // not constant (nt runtime)
            const int s2 = (s + 2 > NT * 8 - 1) ? (NT * 8 - 1) : (s + 2);

            if ((kt & 1) == 0) {
                __builtin_amdgcn_s_setprio(1);
                #pragma unroll
                for (int mi = 0; mi < 4; ++mi)
                    #pragma unroll
                    for (int ni = 0; ni < 4; ++ni)
                        acc[mi][ni] = __builtin_amdgcn_mfma_f32_16x16x32_bf16(
                            aX[mi], bX[ni], acc[mi][ni], 0, 0, 0);
                __builtin_amdgcn_s_setprio(0);
                LDA(aX, s2); LDB(bX, s2);          // refill X for step s+2
            } else {
                __builtin_amdgcn_s_setprio(1);
                #pragma unroll
                for (int mi = 0; mi < 4; ++mi)
                    #pragma unroll
                    for (int ni = 0; ni < 4; ++ni)
                        acc[mi][ni] = __builtin_amdgcn_mfma_f32_16x16x32_bf16(
                            aY[mi], bY[ni], acc[mi][ni], 0, 0, 0);
                __builtin_amdgcn_s_setprio(0);
                LDA(aY, s2); LDB(bY, s2);          // refill Y for step s+2
            }
        }

        // per-tile epilogue: exp + in-lane partial sums (A pre-scaled by 2)
        #pragma unroll
        for (int mi = 0; mi < 4; ++mi)
            #pragma unroll
            for (int r = 0; r < 4; ++r) {
                float s = 0.f;
                #pragma unroll
                for (int ni = 0; ni < 4; ++ni)
                    s += __expf(acc[mi][ni][r]);
                partAcc[mi][r] += s;
            }
    }
    #undef LDA
    #undef LDB

    // block epilogue: reduce across the 16 column-lanes, one atomic set
    #pragma unroll
    for (int off = 1; off <= 8; off <<= 1)
        #pragma unroll
        for (int mi = 0; mi < 4; ++mi)
            #pragma unroll
            for (int r = 0; r < 4; ++r)
                partAcc[mi][r] += __shfl_xor(partAcc[mi][r], off);

    if ((l & 15) == 0) {
        const int rg = (l >> 4) * 4;     // C/D layout: row = (l>>4)*4 + reg
        #pragma unroll
        for (int mi = 0; mi < 4; ++mi)
            #pragma unroll
            for (int r = 0; r < 4; ++r)
                atomicAdd(&rowsum[rowBase + wr * 64 + mi * 16 + rg + r],
                          partAcc[mi][r]);
    }
}

// ---------------------------------------------------------------------------
// Kernel 3: loss = mean_b [ log(exp(pos_b) + rowsum_b) - pos_b ]
// ---------------------------------------------------------------------------
__global__ __launch_bounds__(1024) void finalize_kernel(
    const float* __restrict__ pos_logit, const float* __restrict__ rowsum,
    float* __restrict__ out, int B)
{
    __shared__ float red[1024];
    float acc = 0.f;
    for (int b = (int)threadIdx.x; b < B; b += 1024) {
        const float pl = pos_logit[b];
        acc += logf(expf(pl) + rowsum[b]) - pl;
    }
    red[threadIdx.x] = acc;
    __syncthreads();
    #pragma unroll
    for (int s = 512; s; s >>= 1) {
        if ((int)threadIdx.x < s) red[threadIdx.x] += red[threadIdx.x + s];
        __syncthreads();
    }
    if (threadIdx.x == 0) out[0] = red[0] / (float)B;
}

// ---------------------------------------------------------------------------
extern "C" void kernel_launch(void* const* d_in, const int* in_sizes, int n_in,
                              void* d_out, int out_size, void* d_ws, size_t ws_size,
                              hipStream_t stream)
{
    const float* ei = (const float*)d_in[0];
    const float* ej = (const float*)d_in[1];
    const float* ek = (const float*)d_in[2];
    const int B = in_sizes[0] / D_DIM;   // 8192

    unsigned short* zip = (unsigned short*)d_ws;            // 4 MB packed
    unsigned short* zkp = zip + (size_t)B * D_DIM;          // 4 MB packed
    float* rowsum       = (float*)(zkp + (size_t)B * D_DIM);
    float* pos_logit    = rowsum + B;

    prep_kernel<<<dim3(B / 16), dim3(256), 0, stream>>>(
        ei, ej, ek, zip, zkp, pos_logit, rowsum);

    dim3 grid(B / (NT * BN), B / BM);    // (16, 64) = 1024 blocks
    sim_mfma_kernel<<<grid, dim3(256), 0, stream>>>(zip, zkp, rowsum);

    finalize_kernel<<<dim3(1), dim3(1024), 0, stream>>>(
        pos_logit, rowsum, (float*)d_out, B);
}